// Round 5
// baseline (634.539 us; speedup 1.0000x reference)
//
#include <hip/hip_runtime.h>
#include <math.h>

namespace {

constexpr int kIn  = 128;
constexpr int kH1  = 512;
constexpr int kH2  = 300;
constexpr int kH2p = 320;   // padded: 8 slices x 40 cols
constexpr int kOut = 10;
constexpr float kEps = 1e-5f;

typedef __attribute__((ext_vector_type(8))) short bf16x8;
typedef __attribute__((ext_vector_type(4))) float f32x4;

__device__ __forceinline__ void atomAddF(float* p, float v) { unsafeAtomicAdd(p, v); }

__device__ __forceinline__ unsigned short f2bf(float f) {  // RNE f32->bf16
  unsigned u = __builtin_bit_cast(unsigned, f);
  unsigned r = u + 0x7fffu + ((u >> 16) & 1u);
  return (unsigned short)(r >> 16);
}
__device__ __forceinline__ float bf2f(unsigned short h) {
  return __builtin_bit_cast(float, (unsigned)h << 16);
}
__device__ __forceinline__ float blo(unsigned u) { return __builtin_bit_cast(float, u << 16); }
__device__ __forceinline__ float bhi(unsigned u) { return __builtin_bit_cast(float, u & 0xffff0000u); }
__device__ __forceinline__ unsigned pk2(float a, float b) {
  return (unsigned)f2bf(a) | ((unsigned)f2bf(b) << 16);
}

__device__ __forceinline__ void fma8(const uint4& q, float w, float* acc) {
  acc[0] = fmaf(blo(q.x), w, acc[0]);
  acc[1] = fmaf(bhi(q.x), w, acc[1]);
  acc[2] = fmaf(blo(q.y), w, acc[2]);
  acc[3] = fmaf(bhi(q.y), w, acc[3]);
  acc[4] = fmaf(blo(q.z), w, acc[4]);
  acc[5] = fmaf(bhi(q.z), w, acc[5]);
  acc[6] = fmaf(blo(q.w), w, acc[6]);
  acc[7] = fmaf(bhi(q.w), w, acc[7]);
}

// BN+ReLU on an 8-bf16 granule (channels c0..c0+7 given as float4 pairs)
__device__ __forceinline__ uint4 bnpack(uint4 q, float4 s0, float4 s1, float4 h0, float4 h1) {
  uint4 r;
  r.x = pk2(fmaxf(fmaf(blo(q.x), s0.x, h0.x), 0.f), fmaxf(fmaf(bhi(q.x), s0.y, h0.y), 0.f));
  r.y = pk2(fmaxf(fmaf(blo(q.y), s0.z, h0.z), 0.f), fmaxf(fmaf(bhi(q.y), s0.w, h0.w), 0.f));
  r.z = pk2(fmaxf(fmaf(blo(q.z), s1.x, h1.x), 0.f), fmaxf(fmaf(bhi(q.z), s1.y, h1.y), 0.f));
  r.w = pk2(fmaxf(fmaf(blo(q.w), s1.z, h1.z), 0.f), fmaxf(fmaf(bhi(q.w), s1.w, h1.w), 0.f));
  return r;
}

// ---------------- fused prep: deg/cnt init, x->bf16 sliced, stats zero, W1T, W2T ----------------
// xbf layout: [8][n][16] bf16 (slice-major, 16 cols/slice)
// W1T: [512][128] bf16 ; W2T: [320][512] bf16 (rows >=300 zero)
__global__ void k_prep(float* __restrict__ deg, int* __restrict__ cnt,
                       const float* __restrict__ x, unsigned short* __restrict__ xbf,
                       float* __restrict__ st,
                       const float* __restrict__ W1, unsigned short* __restrict__ W1T,
                       const float* __restrict__ W2, unsigned short* __restrict__ W2T, int n) {
  int i = blockIdx.x * blockDim.x + threadIdx.x;
  if (i < n) { deg[i] = 1.0f; cnt[i] = 0; }
  if (i < 4096) st[i] = 0.f;
  if (i < kIn * kH1) {  // W1T
    int nn = i / kIn, k = i - nn * kIn;
    W1T[i] = f2bf(W1[(size_t)k * kH1 + nn]);
  }
  if (i < kH2p * kH1) {  // W2T
    int nn = i / kH1, k = i - nn * kH1;
    W2T[i] = (nn < kH2) ? f2bf(W2[(size_t)k * kH2 + nn]) : (unsigned short)0;
  }
  if (i < n * 16) {  // xbf: granule i -> node, g
    int node = i >> 4, g = i & 15;           // g: 0..15 (8 f32 each)
    const float4* xp = reinterpret_cast<const float4*>(x + (size_t)node * kIn + g * 8);
    float4 v0 = xp[0], v1 = xp[1];
    uint4 o;
    o.x = pk2(v0.x, v0.y); o.y = pk2(v0.z, v0.w);
    o.z = pk2(v1.x, v1.y); o.w = pk2(v1.z, v1.w);
    int slice = g >> 1, win = g & 1;
    reinterpret_cast<uint4*>(xbf)[((size_t)slice * n + node) * 2 + win] = o;
  }
}

// ---------------- degree / counting ----------------
__global__ void k_deg_cnt(float* __restrict__ deg, int* __restrict__ cnt,
                          const int* __restrict__ ei, const float* __restrict__ w, int nE) {
  int i = blockIdx.x * blockDim.x + threadIdx.x;
  if (i < nE) {
    int c = ei[nE + i];
    atomAddF(&deg[c], w[i]);
    atomicAdd(&cnt[c], 1);
  }
}

__global__ void k_dis(float* __restrict__ deg, int n) {
  int i = blockIdx.x * blockDim.x + threadIdx.x;
  if (i < n) deg[i] = rsqrtf(deg[i]);
}

// single-block in-place exclusive scan
__global__ __launch_bounds__(1024) void k_scan(int* __restrict__ cnt, int n) {
  __shared__ int wsum[16];
  __shared__ int woff[17];
  const int lane = threadIdx.x & 63;
  const int wid  = threadIdx.x >> 6;
  int carry = 0;
  const int nchunk = (n + 1023) >> 10;
  for (int ch = 0; ch < nchunk; ++ch) {
    int i = (ch << 10) + threadIdx.x;
    int v = (i < n) ? cnt[i] : 0;
    int s = v;
#pragma unroll
    for (int off = 1; off < 64; off <<= 1) {
      int t = __shfl_up(s, off);
      if (lane >= off) s += t;
    }
    if (lane == 63) wsum[wid] = s;
    __syncthreads();
    if (wid == 0 && lane < 16) {
      int u = wsum[lane];
#pragma unroll
      for (int off = 1; off < 16; off <<= 1) {
        int q = __shfl_up(u, off);
        if (lane >= off) u += q;
      }
      woff[lane + 1] = u;
      if (lane == 0) woff[0] = 0;
    }
    __syncthreads();
    int excl = s - v + woff[wid] + carry;
    if (i < n) cnt[i] = excl;
    carry += woff[16];
    __syncthreads();
  }
}

__global__ void k_scatter(int* __restrict__ cnt, const int* __restrict__ ei,
                          const float* __restrict__ w, const float* __restrict__ dis,
                          uint2* __restrict__ pr, int nE) {
  int i = blockIdx.x * blockDim.x + threadIdx.x;
  if (i < nE) {
    int r = ei[i];
    int c = ei[nE + i];
    int pos = atomicAdd(&cnt[c], 1);
    float ww = dis[r] * w[i] * dis[c];
    pr[pos] = make_uint2((unsigned)r, __builtin_bit_cast(unsigned, ww));
  }
}

// ---------------- sliced gather: slice = blockIdx.x & 7 (XCD-pinned) ----------------
// X: [8][n][NSQ*8] bf16 slice-major. out: row-major bf16, row stride outStride shorts.
template<int NSQ>
__global__ void k_gather(const unsigned short* __restrict__ X, const int* __restrict__ endp,
                         const uint2* __restrict__ pr, const float* __restrict__ dis,
                         unsigned short* __restrict__ out, int n, int outStride) {
  const int slice = blockIdx.x & 7;
  const int tid = (blockIdx.x >> 3) * blockDim.x + threadIdx.x;
  int v = tid / NSQ;
  int s = tid - v * NSQ;
  if (v >= n) return;
  const uint4* Xr = reinterpret_cast<const uint4*>(X) + (size_t)slice * n * NSQ;
  int beg = (v == 0) ? 0 : endp[v - 1];
  int end = endp[v];
  float d = dis[v];
  float sw = d * d;
  float acc[8];
  {
    uint4 q = Xr[(size_t)v * NSQ + s];
    acc[0] = blo(q.x) * sw; acc[1] = bhi(q.x) * sw;
    acc[2] = blo(q.y) * sw; acc[3] = bhi(q.y) * sw;
    acc[4] = blo(q.z) * sw; acc[5] = bhi(q.z) * sw;
    acc[6] = blo(q.w) * sw; acc[7] = bhi(q.w) * sw;
  }
  int e = beg;
  for (; e + 4 <= end; e += 4) {
    uint2 p0 = pr[e], p1 = pr[e + 1], p2 = pr[e + 2], p3 = pr[e + 3];
    uint4 q0 = Xr[(size_t)p0.x * NSQ + s];
    uint4 q1 = Xr[(size_t)p1.x * NSQ + s];
    uint4 q2 = Xr[(size_t)p2.x * NSQ + s];
    uint4 q3 = Xr[(size_t)p3.x * NSQ + s];
    fma8(q0, __builtin_bit_cast(float, p0.y), acc);
    fma8(q1, __builtin_bit_cast(float, p1.y), acc);
    fma8(q2, __builtin_bit_cast(float, p2.y), acc);
    fma8(q3, __builtin_bit_cast(float, p3.y), acc);
  }
  for (; e < end; ++e) {
    uint2 p = pr[e];
    uint4 q = Xr[(size_t)p.x * NSQ + s];
    fma8(q, __builtin_bit_cast(float, p.y), acc);
  }
  uint4 o;
  o.x = pk2(acc[0], acc[1]);
  o.y = pk2(acc[2], acc[3]);
  o.z = pk2(acc[4], acc[5]);
  o.w = pk2(acc[6], acc[7]);
  *reinterpret_cast<uint4*>(out + (size_t)v * outStride + slice * (NSQ * 8) + s * 8) = o;
}

// ---------------- bf16 MFMA GEMM ----------------
// C = A[M,K] @ BT[Nlog,K]^T. FUSE_BN: A <- relu(A*sc+sh) at staging.
// SLICED_OUT: C written as [8][M][40] bf16 (col slice = col/40), else row-major [M][Nlog].
template<bool FUSE_BN, bool SLICED_OUT>
__global__ __launch_bounds__(256) void k_gemm(const unsigned short* __restrict__ A,
    const unsigned short* __restrict__ BT, unsigned short* __restrict__ C,
    const float* __restrict__ sc, const float* __restrict__ sh,
    int M, int Nlog, int K) {
  constexpr int BM = 128, BN = 128, BK = 32;
  __shared__ unsigned short lA[(BK / 8) * BM * 8];
  __shared__ unsigned short lB[(BK / 8) * BN * 8];
  const int tid  = threadIdx.x;
  const int lane = tid & 63;
  const int wid  = tid >> 6;
  const int wr   = wid >> 1;
  const int wc   = wid & 1;
  const int m0 = blockIdx.x * BM;
  const int n0 = blockIdx.y * BN;

  const int sm  = tid >> 2;
  const int sk8 = tid & 3;
  const int fr = lane & 15, fq = lane >> 4;

  const int r0 = m0 + sm, r1 = m0 + sm + 64;
  const bool ok0 = r0 < M, ok1 = r1 < M;
  const int c0r = n0 + sm, c1r = n0 + sm + 64;
  const bool okb0 = c0r < Nlog, okb1 = c1r < Nlog;

  f32x4 acc[4][4] = {};

  for (int k0 = 0; k0 < K; k0 += BK) {
    uint4 a0, a1, b0, b1;
    const uint4 z = make_uint4(0, 0, 0, 0);
    const int kk0 = k0 + sk8 * 8;
    a0 = ok0 ? *reinterpret_cast<const uint4*>(A + (size_t)r0 * K + kk0) : z;
    a1 = ok1 ? *reinterpret_cast<const uint4*>(A + (size_t)r1 * K + kk0) : z;
    b0 = okb0 ? *reinterpret_cast<const uint4*>(BT + (size_t)c0r * K + kk0) : z;
    b1 = okb1 ? *reinterpret_cast<const uint4*>(BT + (size_t)c1r * K + kk0) : z;
    if constexpr (FUSE_BN) {
      float4 s0 = *reinterpret_cast<const float4*>(sc + kk0);
      float4 s1 = *reinterpret_cast<const float4*>(sc + kk0 + 4);
      float4 h0 = *reinterpret_cast<const float4*>(sh + kk0);
      float4 h1 = *reinterpret_cast<const float4*>(sh + kk0 + 4);
      if (ok0) a0 = bnpack(a0, s0, s1, h0, h1);
      if (ok1) a1 = bnpack(a1, s0, s1, h0, h1);
    }
    __syncthreads();
    *reinterpret_cast<uint4*>(lA + (sk8 * BM + sm) * 8)      = a0;
    *reinterpret_cast<uint4*>(lA + (sk8 * BM + sm + 64) * 8) = a1;
    *reinterpret_cast<uint4*>(lB + (sk8 * BN + sm) * 8)      = b0;
    *reinterpret_cast<uint4*>(lB + (sk8 * BN + sm + 64) * 8) = b1;
    __syncthreads();

    bf16x8 af[4], bfr[4];
#pragma unroll
    for (int m = 0; m < 4; ++m)
      af[m] = *reinterpret_cast<const bf16x8*>(lA + (fq * BM + wr * 64 + m * 16 + fr) * 8);
#pragma unroll
    for (int nn = 0; nn < 4; ++nn)
      bfr[nn] = *reinterpret_cast<const bf16x8*>(lB + (fq * BN + wc * 64 + nn * 16 + fr) * 8);
#pragma unroll
    for (int m = 0; m < 4; ++m)
#pragma unroll
      for (int nn = 0; nn < 4; ++nn)
        acc[m][nn] = __builtin_amdgcn_mfma_f32_16x16x32_bf16(af[m], bfr[nn], acc[m][nn], 0, 0, 0);
  }

#pragma unroll
  for (int m = 0; m < 4; ++m) {
#pragma unroll
    for (int r = 0; r < 4; ++r) {
      int row = m0 + wr * 64 + m * 16 + fq * 4 + r;
      if (row >= M) continue;
#pragma unroll
      for (int nn = 0; nn < 4; ++nn) {
        int col = n0 + wc * 64 + nn * 16 + fr;
        if (col < Nlog) {
          unsigned short v = f2bf(acc[m][nn][r]);
          if constexpr (SLICED_OUT) {
            int slice = col / 40, cw = col - slice * 40;
            C[((size_t)slice * M + row) * 40 + cw] = v;
          } else {
            C[(size_t)row * Nlog + col] = v;
          }
        }
      }
    }
  }
}

// ---------------- BatchNorm stats / finalize ----------------
__global__ void k_bn_stats_bf16(const unsigned short* __restrict__ H, float* __restrict__ s1,
                                float* __restrict__ s2, int n, int C, int stride, int rpb) {
  int r0 = blockIdx.x * rpb;
  int r1 = r0 + rpb;
  if (r1 > n) r1 = n;
  for (int c = threadIdx.x; c < C; c += blockDim.x) {
    float a = 0.f, b = 0.f;
    for (int r = r0; r < r1; ++r) {
      float v = bf2f(H[(size_t)r * stride + c]);
      a += v;
      b = fmaf(v, v, b);
    }
    atomAddF(&s1[c], a);
    atomAddF(&s2[c], b);
  }
}

__global__ void k_bn_finalize(const float* __restrict__ s1, const float* __restrict__ s2,
                              const float* __restrict__ g, const float* __restrict__ beta,
                              float* __restrict__ scale, float* __restrict__ shift,
                              int C, float invN) {
  int c = blockIdx.x * blockDim.x + threadIdx.x;
  if (c >= C) return;
  float mean = s1[c] * invN;
  float var = fmaxf(s2[c] * invN - mean * mean, 0.f);
  float sc = g[c] * rsqrtf(var + kEps);
  scale[c] = sc;
  shift[c] = beta[c] - mean * sc;
}

// ---------------- head: BN2-apply + relu + @Wl + bl + relu + log_softmax ----------------
__global__ __launch_bounds__(256) void k_head(const unsigned short* __restrict__ H,
    const float* __restrict__ scale, const float* __restrict__ shift,
    const float* __restrict__ Wl, const float* __restrict__ bl,
    float* __restrict__ out, int n) {
  __shared__ float sW[kH2 * kOut];
  __shared__ float sScale[kH2], sShift[kH2];
  for (int i = threadIdx.x; i < kH2 * kOut; i += blockDim.x) sW[i] = Wl[i];
  for (int i = threadIdx.x; i < kH2; i += blockDim.x) {
    sScale[i] = scale[i];
    sShift[i] = shift[i];
  }
  __syncthreads();
  float blv[kOut];
#pragma unroll
  for (int j = 0; j < kOut; ++j) blv[j] = bl[j];
  const int lane = threadIdx.x & 63;
  const int wid = (blockIdx.x * blockDim.x + threadIdx.x) >> 6;
  const int nw  = (gridDim.x * blockDim.x) >> 6;
  for (int node = wid; node < n; node += nw) {
    const unsigned short* hrow = H + (size_t)node * kH2p;
    float acc[kOut] = {};
    for (int k = lane; k < kH2; k += 64) {
      float v = fmaxf(fmaf(bf2f(hrow[k]), sScale[k], sShift[k]), 0.f);
      const float* wr = sW + k * kOut;
#pragma unroll
      for (int j = 0; j < kOut; ++j) acc[j] = fmaf(v, wr[j], acc[j]);
    }
#pragma unroll
    for (int j = 0; j < kOut; ++j) {
      float v = acc[j];
      for (int off = 32; off > 0; off >>= 1) v += __shfl_down(v, off);
      acc[j] = v;
    }
    if (lane == 0) {
      float vv[kOut], m = -1e30f;
#pragma unroll
      for (int j = 0; j < kOut; ++j) {
        vv[j] = fmaxf(acc[j] + blv[j], 0.f);
        m = fmaxf(m, vv[j]);
      }
      float s = 0.f;
#pragma unroll
      for (int j = 0; j < kOut; ++j) s += expf(vv[j] - m);
      float lse = m + logf(s);
      float* o = out + (size_t)node * kOut;
#pragma unroll
      for (int j = 0; j < kOut; ++j) o[j] = vv[j] - lse;
    }
  }
}

}  // namespace

extern "C" void kernel_launch(void* const* d_in, const int* in_sizes, int n_in,
                              void* d_out, int out_size, void* d_ws, size_t ws_size,
                              hipStream_t stream) {
  const float* x   = (const float*)d_in[0];
  const int*   ei  = (const int*)d_in[1];
  const float* ew  = (const float*)d_in[2];
  const float* W1  = (const float*)d_in[3];
  // d_in[4] = b1: constant per column -> cancelled by BN1 mean subtraction
  const float* g1  = (const float*)d_in[5];
  const float* be1 = (const float*)d_in[6];
  const float* W2  = (const float*)d_in[7];
  // d_in[8] = b2: cancelled by BN2
  const float* g2  = (const float*)d_in[9];
  const float* be2 = (const float*)d_in[10];
  const float* Wl  = (const float*)d_in[11];
  const float* bl  = (const float*)d_in[12];
  float* out = (float*)d_out;
  float* ws  = (float*)d_ws;

  const int n = in_sizes[0] / kIn;  // 50000
  const int e = in_sizes[1] / 2;    // 800000

  // workspace (float units), ~148 MB total:
  float* dis = ws;                                         // 50048
  int*   cnt = (int*)(ws + 50048);                         // 50048
  uint2* pr  = (uint2*)(ws + 100096);                      // 800000 pairs
  float* st  = ws + 1700096;                               // 4096
  float* s1a = st,        *s2a = st + 512,  *sc1 = st + 1024, *sh1 = st + 1536;
  float* s1b = st + 2048, *s2b = st + 2560, *sc2 = st + 3072, *sh2 = st + 3584;
  unsigned short* xbf = (unsigned short*)(ws + 1704192);   // [8][n][16] = 3.2M fl
  unsigned short* W1T = (unsigned short*)(ws + 4904192);   // 512x128 = 32768 fl
  unsigned short* W2T = (unsigned short*)(ws + 4936960);   // 320x512 = 81920 fl
  unsigned short* agg1 = (unsigned short*)(ws + 5018880);  // [n][128] = 3.2M fl
  unsigned short* h1   = (unsigned short*)(ws + 8218880);  // [n][512] = 12.8M fl
  unsigned short* t2   = (unsigned short*)(ws + 21018880); // [8][n][40] = 8M fl
  unsigned short* agg2 = (unsigned short*)(ws + 29018880); // [n][320] = 8M fl

  constexpr int TPB = 256;

  // ---- fused prep + CSC build ----
  k_prep<<<(n * 16 + TPB - 1) / TPB, TPB, 0, stream>>>(dis, cnt, x, xbf, st, W1, W1T, W2, W2T, n);
  k_deg_cnt<<<(e + TPB - 1) / TPB, TPB, 0, stream>>>(dis, cnt, ei, ew, e);
  k_dis<<<(n + TPB - 1) / TPB, TPB, 0, stream>>>(dis, n);
  k_scan<<<1, 1024, 0, stream>>>(cnt, n);
  k_scatter<<<(e + TPB - 1) / TPB, TPB, 0, stream>>>(cnt, ei, ew, dis, pr, e);

  // ---- layer 1: agg1 = A(x); h1 = bf16(agg1@W1); BN1 stats ----
  {
    int bps = (n * 2 + TPB - 1) / TPB;  // NSQ=2 (16 cols/slice)
    k_gather<2><<<bps * 8, TPB, 0, stream>>>(xbf, cnt, pr, dis, agg1, n, kIn);
  }
  {
    dim3 g((n + 127) / 128, kH1 / 128);
    k_gemm<false, false><<<g, 256, 0, stream>>>(agg1, W1T, h1, nullptr, nullptr, n, kH1, kIn);
  }
  k_bn_stats_bf16<<<512, 256, 0, stream>>>(h1, s1a, s2a, n, kH1, kH1, (n + 511) / 512);
  k_bn_finalize<<<(kH1 + 255) / 256, 256, 0, stream>>>(s1a, s2a, g1, be1, sc1, sh1, kH1, 1.0f / n);

  // ---- layer 2: t2 = bf16(relu(bn(h1))@W2) sliced; agg2 = A(t2); BN2 stats ----
  {
    dim3 g((n + 127) / 128, (kH2p + 127) / 128);
    k_gemm<true, true><<<g, 256, 0, stream>>>(h1, W2T, t2, sc1, sh1, n, kH2p, kH1);
  }
  {
    int bps = (n * 5 + TPB - 1) / TPB;  // NSQ=5 (40 cols/slice)
    k_gather<5><<<bps * 8, TPB, 0, stream>>>(t2, cnt, pr, dis, agg2, n, kH2p);
  }
  k_bn_stats_bf16<<<512, 256, 0, stream>>>(agg2, s1b, s2b, n, kH2, kH2p, (n + 511) / 512);
  k_bn_finalize<<<(kH2 + 255) / 256, 256, 0, stream>>>(s1b, s2b, g2, be2, sc2, sh2, kH2, 1.0f / n);

  // ---- head ----
  k_head<<<1024, 256, 0, stream>>>(agg2, sc2, sh2, Wl, bl, out, n);
}

// Round 6
// 592.910 us; speedup vs baseline: 1.0702x; 1.0702x over previous
//
#include <hip/hip_runtime.h>
#include <math.h>

namespace {

constexpr int kIn  = 128;
constexpr int kH1  = 512;
constexpr int kH2  = 300;
constexpr int kH2p = 304;   // padded to 16B granule
constexpr int kOut = 10;
constexpr float kEps = 1e-5f;

typedef __attribute__((ext_vector_type(8))) short bf16x8;
typedef __attribute__((ext_vector_type(4))) float f32x4;

__device__ __forceinline__ void atomAddF(float* p, float v) { unsafeAtomicAdd(p, v); }

__device__ __forceinline__ unsigned short f2bf(float f) {  // RNE f32->bf16
  unsigned u = __builtin_bit_cast(unsigned, f);
  unsigned r = u + 0x7fffu + ((u >> 16) & 1u);
  return (unsigned short)(r >> 16);
}
__device__ __forceinline__ float bf2f(unsigned short h) {
  return __builtin_bit_cast(float, (unsigned)h << 16);
}
__device__ __forceinline__ float blo(unsigned u) { return __builtin_bit_cast(float, u << 16); }
__device__ __forceinline__ float bhi(unsigned u) { return __builtin_bit_cast(float, u & 0xffff0000u); }
__device__ __forceinline__ unsigned pk2(float a, float b) {
  return (unsigned)f2bf(a) | ((unsigned)f2bf(b) << 16);
}

__device__ __forceinline__ void fma8(const uint4& q, float w, float* acc) {
  acc[0] = fmaf(blo(q.x), w, acc[0]);
  acc[1] = fmaf(bhi(q.x), w, acc[1]);
  acc[2] = fmaf(blo(q.y), w, acc[2]);
  acc[3] = fmaf(bhi(q.y), w, acc[3]);
  acc[4] = fmaf(blo(q.z), w, acc[4]);
  acc[5] = fmaf(bhi(q.z), w, acc[5]);
  acc[6] = fmaf(blo(q.w), w, acc[6]);
  acc[7] = fmaf(bhi(q.w), w, acc[7]);
}

// BN+ReLU on an 8-bf16 granule
__device__ __forceinline__ uint4 bnpack(uint4 q, float4 s0, float4 s1, float4 h0, float4 h1) {
  uint4 r;
  r.x = pk2(fmaxf(fmaf(blo(q.x), s0.x, h0.x), 0.f), fmaxf(fmaf(bhi(q.x), s0.y, h0.y), 0.f));
  r.y = pk2(fmaxf(fmaf(blo(q.y), s0.z, h0.z), 0.f), fmaxf(fmaf(bhi(q.y), s0.w, h0.w), 0.f));
  r.z = pk2(fmaxf(fmaf(blo(q.z), s1.x, h1.x), 0.f), fmaxf(fmaf(bhi(q.z), s1.y, h1.y), 0.f));
  r.w = pk2(fmaxf(fmaf(blo(q.w), s1.z, h1.z), 0.f), fmaxf(fmaf(bhi(q.w), s1.w, h1.w), 0.f));
  return r;
}

// ---------------- fused prep: deg/cnt init, stats zero, x->bf16 row-major, W1T, W2T ----------------
__global__ void k_prep(float* __restrict__ deg, int* __restrict__ cnt,
                       const float* __restrict__ x, unsigned short* __restrict__ xbf,
                       float* __restrict__ st,
                       const float* __restrict__ W1, unsigned short* __restrict__ W1T,
                       const float* __restrict__ W2, unsigned short* __restrict__ W2T, int n) {
  int i = blockIdx.x * blockDim.x + threadIdx.x;
  if (i < n) { deg[i] = 1.0f; cnt[i] = 0; }
  if (i < 4096) st[i] = 0.f;
  if (i < kIn * kH1) {  // W1T[512][128]
    int nn = i / kIn, k = i - nn * kIn;
    W1T[i] = f2bf(W1[(size_t)k * kH1 + nn]);
  }
  if (i < kH2p * kH1) {  // W2T[304][512], rows >=300 zero
    int nn = i / kH1, k = i - nn * kH1;
    W2T[i] = (nn < kH2) ? f2bf(W2[(size_t)k * kH2 + nn]) : (unsigned short)0;
  }
  if (i < n * 16) {  // xbf row-major [n][128]: granule i
    int node = i >> 4, g = i & 15;
    const float4* xp = reinterpret_cast<const float4*>(x + (size_t)node * kIn + g * 8);
    float4 v0 = xp[0], v1 = xp[1];
    uint4 o;
    o.x = pk2(v0.x, v0.y); o.y = pk2(v0.z, v0.w);
    o.z = pk2(v1.x, v1.y); o.w = pk2(v1.z, v1.w);
    reinterpret_cast<uint4*>(xbf)[i] = o;
  }
}

// ---------------- degree / counting ----------------
__global__ void k_deg_cnt(float* __restrict__ deg, int* __restrict__ cnt,
                          const int* __restrict__ ei, const float* __restrict__ w, int nE) {
  int i = blockIdx.x * blockDim.x + threadIdx.x;
  if (i < nE) {
    int c = ei[nE + i];
    atomAddF(&deg[c], w[i]);
    atomicAdd(&cnt[c], 1);
  }
}

__global__ void k_dis(float* __restrict__ deg, int n) {
  int i = blockIdx.x * blockDim.x + threadIdx.x;
  if (i < n) deg[i] = rsqrtf(deg[i]);
}

// single-block in-place exclusive scan
__global__ __launch_bounds__(1024) void k_scan(int* __restrict__ cnt, int n) {
  __shared__ int wsum[16];
  __shared__ int woff[17];
  const int lane = threadIdx.x & 63;
  const int wid  = threadIdx.x >> 6;
  int carry = 0;
  const int nchunk = (n + 1023) >> 10;
  for (int ch = 0; ch < nchunk; ++ch) {
    int i = (ch << 10) + threadIdx.x;
    int v = (i < n) ? cnt[i] : 0;
    int s = v;
#pragma unroll
    for (int off = 1; off < 64; off <<= 1) {
      int t = __shfl_up(s, off);
      if (lane >= off) s += t;
    }
    if (lane == 63) wsum[wid] = s;
    __syncthreads();
    if (wid == 0 && lane < 16) {
      int u = wsum[lane];
#pragma unroll
      for (int off = 1; off < 16; off <<= 1) {
        int q = __shfl_up(u, off);
        if (lane >= off) u += q;
      }
      woff[lane + 1] = u;
      if (lane == 0) woff[0] = 0;
    }
    __syncthreads();
    int excl = s - v + woff[wid] + carry;
    if (i < n) cnt[i] = excl;
    carry += woff[16];
    __syncthreads();
  }
}

__global__ void k_scatter(int* __restrict__ cnt, const int* __restrict__ ei,
                          const float* __restrict__ w, const float* __restrict__ dis,
                          uint2* __restrict__ pr, int nE) {
  int i = blockIdx.x * blockDim.x + threadIdx.x;
  if (i < nE) {
    int r = ei[i];
    int c = ei[nE + i];
    int pos = atomicAdd(&cnt[c], 1);
    float ww = dis[r] * w[i] * dis[c];
    pr[pos] = make_uint2((unsigned)r, __builtin_bit_cast(unsigned, ww));
  }
}

// ---------------- gather propagate: bf16 in/out, 16B granules, 4x unrolled ----------------
template<int NSQ>  // uint4 granules per row
__global__ void k_gather(const unsigned short* __restrict__ X, const int* __restrict__ endp,
                         const uint2* __restrict__ pr, const float* __restrict__ dis,
                         unsigned short* __restrict__ out, int n) {
  int tid = blockIdx.x * blockDim.x + threadIdx.x;
  int v = tid / NSQ;
  int s = tid - v * NSQ;
  if (v >= n) return;
  int beg = (v == 0) ? 0 : endp[v - 1];
  int end = endp[v];
  const uint4* Xr = reinterpret_cast<const uint4*>(X);
  float d = dis[v];
  float sw = d * d;
  float acc[8];
  {
    uint4 q = Xr[(size_t)v * NSQ + s];
    acc[0] = blo(q.x) * sw; acc[1] = bhi(q.x) * sw;
    acc[2] = blo(q.y) * sw; acc[3] = bhi(q.y) * sw;
    acc[4] = blo(q.z) * sw; acc[5] = bhi(q.z) * sw;
    acc[6] = blo(q.w) * sw; acc[7] = bhi(q.w) * sw;
  }
  int e = beg;
  for (; e + 4 <= end; e += 4) {
    uint2 p0 = pr[e], p1 = pr[e + 1], p2 = pr[e + 2], p3 = pr[e + 3];
    uint4 q0 = Xr[(size_t)p0.x * NSQ + s];
    uint4 q1 = Xr[(size_t)p1.x * NSQ + s];
    uint4 q2 = Xr[(size_t)p2.x * NSQ + s];
    uint4 q3 = Xr[(size_t)p3.x * NSQ + s];
    fma8(q0, __builtin_bit_cast(float, p0.y), acc);
    fma8(q1, __builtin_bit_cast(float, p1.y), acc);
    fma8(q2, __builtin_bit_cast(float, p2.y), acc);
    fma8(q3, __builtin_bit_cast(float, p3.y), acc);
  }
  for (; e < end; ++e) {
    uint2 p = pr[e];
    uint4 q = Xr[(size_t)p.x * NSQ + s];
    fma8(q, __builtin_bit_cast(float, p.y), acc);
  }
  uint4 o;
  o.x = pk2(acc[0], acc[1]);
  o.y = pk2(acc[2], acc[3]);
  o.z = pk2(acc[4], acc[5]);
  o.w = pk2(acc[6], acc[7]);
  reinterpret_cast<uint4*>(out)[(size_t)v * NSQ + s] = o;
}

// ---------------- bf16 MFMA GEMM: C[M,Nlog] = A[M,K] @ BT[Nlog,K]^T ----------------
// 1D grid, col-tile fastest + bijective XCD chunk swizzle: the ntiles col-blocks of one
// M-tile are consecutive logical blocks -> co-resident on one XCD -> A-tile L2 reuse.
// FUSE_BN: A <- relu(A*sc+sh) at staging.
template<bool FUSE_BN>
__global__ __launch_bounds__(256) void k_gemm(const unsigned short* __restrict__ A,
    const unsigned short* __restrict__ BT, unsigned short* __restrict__ C,
    const float* __restrict__ sc, const float* __restrict__ sh,
    int M, int Nlog, int K, int ntiles, int nwg) {
  constexpr int BM = 128, BN = 128, BK = 32;
  __shared__ unsigned short lA[(BK / 8) * BM * 8];
  __shared__ unsigned short lB[(BK / 8) * BN * 8];

  // bijective XCD chunk swizzle (m204): physical p -> logical chunked per XCD
  int p = blockIdx.x;
  int xcd = p & 7, idx = p >> 3;
  int q8 = nwg >> 3, r8 = nwg & 7;
  int logical = (xcd < r8 ? xcd * (q8 + 1) : r8 * (q8 + 1) + (xcd - r8) * q8) + idx;
  const int nt = logical % ntiles;
  const int mt = logical / ntiles;

  const int tid  = threadIdx.x;
  const int lane = tid & 63;
  const int wid  = tid >> 6;
  const int wr   = wid >> 1;
  const int wc   = wid & 1;
  const int m0 = mt * BM;
  const int n0 = nt * BN;

  const int sm  = tid >> 2;
  const int sk8 = tid & 3;
  const int fr = lane & 15, fq = lane >> 4;

  const int r0 = m0 + sm, r1 = m0 + sm + 64;
  const bool ok0 = r0 < M, ok1 = r1 < M;
  const int c0r = n0 + sm, c1r = n0 + sm + 64;
  const bool okb0 = c0r < Nlog, okb1 = c1r < Nlog;

  f32x4 acc[4][4] = {};

  for (int k0 = 0; k0 < K; k0 += BK) {
    uint4 a0, a1, b0, b1;
    const uint4 z = make_uint4(0, 0, 0, 0);
    const int kk0 = k0 + sk8 * 8;
    a0 = ok0 ? *reinterpret_cast<const uint4*>(A + (size_t)r0 * K + kk0) : z;
    a1 = ok1 ? *reinterpret_cast<const uint4*>(A + (size_t)r1 * K + kk0) : z;
    b0 = okb0 ? *reinterpret_cast<const uint4*>(BT + (size_t)c0r * K + kk0) : z;
    b1 = okb1 ? *reinterpret_cast<const uint4*>(BT + (size_t)c1r * K + kk0) : z;
    if constexpr (FUSE_BN) {
      float4 s0 = *reinterpret_cast<const float4*>(sc + kk0);
      float4 s1 = *reinterpret_cast<const float4*>(sc + kk0 + 4);
      float4 h0 = *reinterpret_cast<const float4*>(sh + kk0);
      float4 h1 = *reinterpret_cast<const float4*>(sh + kk0 + 4);
      if (ok0) a0 = bnpack(a0, s0, s1, h0, h1);
      if (ok1) a1 = bnpack(a1, s0, s1, h0, h1);
    }
    __syncthreads();
    *reinterpret_cast<uint4*>(lA + (sk8 * BM + sm) * 8)      = a0;
    *reinterpret_cast<uint4*>(lA + (sk8 * BM + sm + 64) * 8) = a1;
    *reinterpret_cast<uint4*>(lB + (sk8 * BN + sm) * 8)      = b0;
    *reinterpret_cast<uint4*>(lB + (sk8 * BN + sm + 64) * 8) = b1;
    __syncthreads();

    bf16x8 af[4], bfr[4];
#pragma unroll
    for (int m = 0; m < 4; ++m)
      af[m] = *reinterpret_cast<const bf16x8*>(lA + (fq * BM + wr * 64 + m * 16 + fr) * 8);
#pragma unroll
    for (int nn = 0; nn < 4; ++nn)
      bfr[nn] = *reinterpret_cast<const bf16x8*>(lB + (fq * BN + wc * 64 + nn * 16 + fr) * 8);
#pragma unroll
    for (int m = 0; m < 4; ++m)
#pragma unroll
      for (int nn = 0; nn < 4; ++nn)
        acc[m][nn] = __builtin_amdgcn_mfma_f32_16x16x32_bf16(af[m], bfr[nn], acc[m][nn], 0, 0, 0);
  }

#pragma unroll
  for (int m = 0; m < 4; ++m) {
#pragma unroll
    for (int r = 0; r < 4; ++r) {
      int row = m0 + wr * 64 + m * 16 + fq * 4 + r;
      if (row >= M) continue;
#pragma unroll
      for (int nn = 0; nn < 4; ++nn) {
        int col = n0 + wc * 64 + nn * 16 + fr;
        if (col < Nlog)
          C[(size_t)row * Nlog + col] = f2bf(acc[m][nn][r]);
      }
    }
  }
}

// ---------------- BatchNorm stats / finalize ----------------
__global__ void k_bn_stats_bf16(const unsigned short* __restrict__ H, float* __restrict__ s1,
                                float* __restrict__ s2, int n, int C, int stride, int rpb) {
  int r0 = blockIdx.x * rpb;
  int r1 = r0 + rpb;
  if (r1 > n) r1 = n;
  for (int c = threadIdx.x; c < C; c += blockDim.x) {
    float a = 0.f, b = 0.f;
    for (int r = r0; r < r1; ++r) {
      float v = bf2f(H[(size_t)r * stride + c]);
      a += v;
      b = fmaf(v, v, b);
    }
    atomAddF(&s1[c], a);
    atomAddF(&s2[c], b);
  }
}

__global__ void k_bn_finalize(const float* __restrict__ s1, const float* __restrict__ s2,
                              const float* __restrict__ g, const float* __restrict__ beta,
                              float* __restrict__ scale, float* __restrict__ shift,
                              int C, float invN) {
  int c = blockIdx.x * blockDim.x + threadIdx.x;
  if (c >= C) return;
  float mean = s1[c] * invN;
  float var = fmaxf(s2[c] * invN - mean * mean, 0.f);
  float sc = g[c] * rsqrtf(var + kEps);
  scale[c] = sc;
  shift[c] = beta[c] - mean * sc;
}

// ---------------- head: BN2-apply + relu + @Wl + bl + relu + log_softmax ----------------
__global__ __launch_bounds__(256) void k_head(const unsigned short* __restrict__ H,
    const float* __restrict__ scale, const float* __restrict__ shift,
    const float* __restrict__ Wl, const float* __restrict__ bl,
    float* __restrict__ out, int n) {
  __shared__ float sW[kH2 * kOut];
  __shared__ float sScale[kH2], sShift[kH2];
  for (int i = threadIdx.x; i < kH2 * kOut; i += blockDim.x) sW[i] = Wl[i];
  for (int i = threadIdx.x; i < kH2; i += blockDim.x) {
    sScale[i] = scale[i];
    sShift[i] = shift[i];
  }
  __syncthreads();
  float blv[kOut];
#pragma unroll
  for (int j = 0; j < kOut; ++j) blv[j] = bl[j];
  const int lane = threadIdx.x & 63;
  const int wid = (blockIdx.x * blockDim.x + threadIdx.x) >> 6;
  const int nw  = (gridDim.x * blockDim.x) >> 6;
  for (int node = wid; node < n; node += nw) {
    const unsigned short* hrow = H + (size_t)node * kH2p;
    float acc[kOut] = {};
    for (int k = lane; k < kH2; k += 64) {
      float v = fmaxf(fmaf(bf2f(hrow[k]), sScale[k], sShift[k]), 0.f);
      const float* wr = sW + k * kOut;
#pragma unroll
      for (int j = 0; j < kOut; ++j) acc[j] = fmaf(v, wr[j], acc[j]);
    }
#pragma unroll
    for (int j = 0; j < kOut; ++j) {
      float v = acc[j];
      for (int off = 32; off > 0; off >>= 1) v += __shfl_down(v, off);
      acc[j] = v;
    }
    if (lane == 0) {
      float vv[kOut], m = -1e30f;
#pragma unroll
      for (int j = 0; j < kOut; ++j) {
        vv[j] = fmaxf(acc[j] + blv[j], 0.f);
        m = fmaxf(m, vv[j]);
      }
      float s = 0.f;
#pragma unroll
      for (int j = 0; j < kOut; ++j) s += expf(vv[j] - m);
      float lse = m + logf(s);
      float* o = out + (size_t)node * kOut;
#pragma unroll
      for (int j = 0; j < kOut; ++j) o[j] = vv[j] - lse;
    }
  }
}

}  // namespace

extern "C" void kernel_launch(void* const* d_in, const int* in_sizes, int n_in,
                              void* d_out, int out_size, void* d_ws, size_t ws_size,
                              hipStream_t stream) {
  const float* x   = (const float*)d_in[0];
  const int*   ei  = (const int*)d_in[1];
  const float* ew  = (const float*)d_in[2];
  const float* W1  = (const float*)d_in[3];
  // d_in[4] = b1: constant per column -> cancelled by BN1 mean subtraction
  const float* g1  = (const float*)d_in[5];
  const float* be1 = (const float*)d_in[6];
  const float* W2  = (const float*)d_in[7];
  // d_in[8] = b2: cancelled by BN2
  const float* g2  = (const float*)d_in[9];
  const float* be2 = (const float*)d_in[10];
  const float* Wl  = (const float*)d_in[11];
  const float* bl  = (const float*)d_in[12];
  float* out = (float*)d_out;
  float* ws  = (float*)d_ws;

  const int n = in_sizes[0] / kIn;  // 50000
  const int e = in_sizes[1] / 2;    // 800000

  // workspace (float units), ~145 MB total:
  float* dis = ws;                                         // 50048
  int*   cnt = (int*)(ws + 50048);                         // 50048
  uint2* pr  = (uint2*)(ws + 100096);                      // 800000 pairs
  float* st  = ws + 1700096;                               // 4096
  float* s1a = st,        *s2a = st + 512,  *sc1 = st + 1024, *sh1 = st + 1536;
  float* s1b = st + 2048, *s2b = st + 2560, *sc2 = st + 3072, *sh2 = st + 3584;
  unsigned short* xbf = (unsigned short*)(ws + 1704192);   // [n][128] = 3.2M fl
  unsigned short* W1T = (unsigned short*)(ws + 4904192);   // 512x128 = 32768 fl
  unsigned short* W2T = (unsigned short*)(ws + 4936960);   // 304x512 = 77824 fl
  unsigned short* agg1 = (unsigned short*)(ws + 5014784);  // [n][128] = 3.2M fl
  unsigned short* h1   = (unsigned short*)(ws + 8214784);  // [n][512] = 12.8M fl
  unsigned short* t2   = (unsigned short*)(ws + 21014784); // [n][304] = 7.6M fl
  unsigned short* agg2 = (unsigned short*)(ws + 28614784); // [n][304] = 7.6M fl

  constexpr int TPB = 256;

  // ---- fused prep + CSC build ----
  k_prep<<<(n * 16 + TPB - 1) / TPB, TPB, 0, stream>>>(dis, cnt, x, xbf, st, W1, W1T, W2, W2T, n);
  k_deg_cnt<<<(e + TPB - 1) / TPB, TPB, 0, stream>>>(dis, cnt, ei, ew, e);
  k_dis<<<(n + TPB - 1) / TPB, TPB, 0, stream>>>(dis, n);
  k_scan<<<1, 1024, 0, stream>>>(cnt, n);
  k_scatter<<<(e + TPB - 1) / TPB, TPB, 0, stream>>>(cnt, ei, ew, dis, pr, e);

  const int mtiles = (n + 127) / 128;  // 391

  // ---- layer 1: agg1 = A(xbf); h1 = bf16(agg1@W1); BN1 stats ----
  {
    int tot = n * (kIn / 8);
    k_gather<kIn / 8><<<(tot + TPB - 1) / TPB, TPB, 0, stream>>>(xbf, cnt, pr, dis, agg1, n);
  }
  {
    int ntiles = kH1 / 128;            // 4
    int nwg = mtiles * ntiles;
    k_gemm<false><<<nwg, 256, 0, stream>>>(agg1, W1T, h1, nullptr, nullptr, n, kH1, kIn, ntiles, nwg);
  }
  k_bn_stats_bf16<<<512, 256, 0, stream>>>(h1, s1a, s2a, n, kH1, kH1, (n + 511) / 512);
  k_bn_finalize<<<(kH1 + 255) / 256, 256, 0, stream>>>(s1a, s2a, g1, be1, sc1, sh1, kH1, 1.0f / n);

  // ---- layer 2: t2 = bf16(relu(bn(h1))@W2); agg2 = A(t2); BN2 stats ----
  {
    int ntiles = (kH2p + 127) / 128;   // 3
    int nwg = mtiles * ntiles;
    k_gemm<true><<<nwg, 256, 0, stream>>>(h1, W2T, t2, sc1, sh1, n, kH2p, kH1, ntiles, nwg);
  }
  {
    int tot = n * (kH2p / 8);
    k_gather<kH2p / 8><<<(tot + TPB - 1) / TPB, TPB, 0, stream>>>(t2, cnt, pr, dis, agg2, n);
  }
  k_bn_stats_bf16<<<512, 256, 0, stream>>>(agg2, s1b, s2b, n, kH2, kH2p, (n + 511) / 512);
  k_bn_finalize<<<(kH2 + 255) / 256, 256, 0, stream>>>(s1b, s2b, g2, be2, sc2, sh2, kH2, 1.0f / n);

  // ---- head ----
  k_head<<<1024, 256, 0, stream>>>(agg2, sc2, sh2, Wl, bl, out, n);
}

// Round 7
// 556.237 us; speedup vs baseline: 1.1408x; 1.0659x over previous
//
#include <hip/hip_runtime.h>
#include <math.h>

namespace {

constexpr int kIn  = 128;
constexpr int kH1  = 512;
constexpr int kH2  = 300;
constexpr int kH2p = 304;   // padded to 16B granule
constexpr int kW2R = 384;   // W2T padded rows (3 x 128 col-tiles)
constexpr int kOut = 10;
constexpr float kEps = 1e-5f;

typedef __attribute__((ext_vector_type(8))) short bf16x8;
typedef __attribute__((ext_vector_type(4))) float f32x4;

__device__ __forceinline__ void atomAddF(float* p, float v) { unsafeAtomicAdd(p, v); }

__device__ __forceinline__ unsigned short f2bf(float f) {  // RNE f32->bf16
  unsigned u = __builtin_bit_cast(unsigned, f);
  unsigned r = u + 0x7fffu + ((u >> 16) & 1u);
  return (unsigned short)(r >> 16);
}
__device__ __forceinline__ float bf2f(unsigned short h) {
  return __builtin_bit_cast(float, (unsigned)h << 16);
}
__device__ __forceinline__ float blo(unsigned u) { return __builtin_bit_cast(float, u << 16); }
__device__ __forceinline__ float bhi(unsigned u) { return __builtin_bit_cast(float, u & 0xffff0000u); }
__device__ __forceinline__ unsigned pk2(float a, float b) {
  return (unsigned)f2bf(a) | ((unsigned)f2bf(b) << 16);
}

// async global(16B) -> LDS DMA; dest must be wave-uniform-base + lane*16 (it is:
// granule id = wave_base + lane in all call sites below).
__device__ __forceinline__ void gload16(const unsigned short* g, unsigned short* l) {
  __builtin_amdgcn_global_load_lds(
      (const __attribute__((address_space(1))) unsigned int*)g,
      (__attribute__((address_space(3))) unsigned int*)l, 16, 0, 0);
}

__device__ __forceinline__ void fma8(const uint4& q, float w, float* acc) {
  acc[0] = fmaf(blo(q.x), w, acc[0]);
  acc[1] = fmaf(bhi(q.x), w, acc[1]);
  acc[2] = fmaf(blo(q.y), w, acc[2]);
  acc[3] = fmaf(bhi(q.y), w, acc[3]);
  acc[4] = fmaf(blo(q.z), w, acc[4]);
  acc[5] = fmaf(bhi(q.z), w, acc[5]);
  acc[6] = fmaf(blo(q.w), w, acc[6]);
  acc[7] = fmaf(bhi(q.w), w, acc[7]);
}

// ---------------- fused prep: deg/cnt init, stats zero, x->bf16, W1T, W2T ----------------
__global__ void k_prep(float* __restrict__ deg, int* __restrict__ cnt,
                       const float* __restrict__ x, unsigned short* __restrict__ xbf,
                       float* __restrict__ st,
                       const float* __restrict__ W1, unsigned short* __restrict__ W1T,
                       const float* __restrict__ W2, unsigned short* __restrict__ W2T, int n) {
  int i = blockIdx.x * blockDim.x + threadIdx.x;
  if (i < n) { deg[i] = 1.0f; cnt[i] = 0; }
  if (i < 4096) st[i] = 0.f;
  if (i < kIn * kH1) {  // W1T[512][128]
    int nn = i / kIn, k = i - nn * kIn;
    W1T[i] = f2bf(W1[(size_t)k * kH1 + nn]);
  }
  if (i < kW2R * kH1) {  // W2T[384][512], rows >=300 zero
    int nn = i / kH1, k = i - nn * kH1;
    W2T[i] = (nn < kH2) ? f2bf(W2[(size_t)k * kH2 + nn]) : (unsigned short)0;
  }
  if (i < n * 16) {  // xbf row-major [n][128]
    int node = i >> 4, g = i & 15;
    const float4* xp = reinterpret_cast<const float4*>(x + (size_t)node * kIn + g * 8);
    float4 v0 = xp[0], v1 = xp[1];
    uint4 o;
    o.x = pk2(v0.x, v0.y); o.y = pk2(v0.z, v0.w);
    o.z = pk2(v1.x, v1.y); o.w = pk2(v1.z, v1.w);
    reinterpret_cast<uint4*>(xbf)[i] = o;
  }
}

// ---------------- degree / counting ----------------
__global__ void k_deg_cnt(float* __restrict__ deg, int* __restrict__ cnt,
                          const int* __restrict__ ei, const float* __restrict__ w, int nE) {
  int i = blockIdx.x * blockDim.x + threadIdx.x;
  if (i < nE) {
    int c = ei[nE + i];
    atomAddF(&deg[c], w[i]);
    atomicAdd(&cnt[c], 1);
  }
}

__global__ void k_dis(float* __restrict__ deg, int n) {
  int i = blockIdx.x * blockDim.x + threadIdx.x;
  if (i < n) deg[i] = rsqrtf(deg[i]);
}

// single-block in-place exclusive scan
__global__ __launch_bounds__(1024) void k_scan(int* __restrict__ cnt, int n) {
  __shared__ int wsum[16];
  __shared__ int woff[17];
  const int lane = threadIdx.x & 63;
  const int wid  = threadIdx.x >> 6;
  int carry = 0;
  const int nchunk = (n + 1023) >> 10;
  for (int ch = 0; ch < nchunk; ++ch) {
    int i = (ch << 10) + threadIdx.x;
    int v = (i < n) ? cnt[i] : 0;
    int s = v;
#pragma unroll
    for (int off = 1; off < 64; off <<= 1) {
      int t = __shfl_up(s, off);
      if (lane >= off) s += t;
    }
    if (lane == 63) wsum[wid] = s;
    __syncthreads();
    if (wid == 0 && lane < 16) {
      int u = wsum[lane];
#pragma unroll
      for (int off = 1; off < 16; off <<= 1) {
        int q = __shfl_up(u, off);
        if (lane >= off) u += q;
      }
      woff[lane + 1] = u;
      if (lane == 0) woff[0] = 0;
    }
    __syncthreads();
    int excl = s - v + woff[wid] + carry;
    if (i < n) cnt[i] = excl;
    carry += woff[16];
    __syncthreads();
  }
}

__global__ void k_scatter(int* __restrict__ cnt, const int* __restrict__ ei,
                          const float* __restrict__ w, const float* __restrict__ dis,
                          uint2* __restrict__ pr, int nE) {
  int i = blockIdx.x * blockDim.x + threadIdx.x;
  if (i < nE) {
    int r = ei[i];
    int c = ei[nE + i];
    int pos = atomicAdd(&cnt[c], 1);
    float ww = dis[r] * w[i] * dis[c];
    pr[pos] = make_uint2((unsigned)r, __builtin_bit_cast(unsigned, ww));
  }
}

// ---------------- gather propagate: bf16 in/out, 16B granules, 4x unrolled ----------------
template<int NSQ>  // uint4 granules per row
__global__ void k_gather(const unsigned short* __restrict__ X, const int* __restrict__ endp,
                         const uint2* __restrict__ pr, const float* __restrict__ dis,
                         unsigned short* __restrict__ out, int n) {
  int tid = blockIdx.x * blockDim.x + threadIdx.x;
  int v = tid / NSQ;
  int s = tid - v * NSQ;
  if (v >= n) return;
  int beg = (v == 0) ? 0 : endp[v - 1];
  int end = endp[v];
  const uint4* Xr = reinterpret_cast<const uint4*>(X);
  float d = dis[v];
  float sw = d * d;
  float acc[8];
  {
    uint4 q = Xr[(size_t)v * NSQ + s];
    acc[0] = blo(q.x) * sw; acc[1] = bhi(q.x) * sw;
    acc[2] = blo(q.y) * sw; acc[3] = bhi(q.y) * sw;
    acc[4] = blo(q.z) * sw; acc[5] = bhi(q.z) * sw;
    acc[6] = blo(q.w) * sw; acc[7] = bhi(q.w) * sw;
  }
  int e = beg;
  for (; e + 4 <= end; e += 4) {
    uint2 p0 = pr[e], p1 = pr[e + 1], p2 = pr[e + 2], p3 = pr[e + 3];
    uint4 q0 = Xr[(size_t)p0.x * NSQ + s];
    uint4 q1 = Xr[(size_t)p1.x * NSQ + s];
    uint4 q2 = Xr[(size_t)p2.x * NSQ + s];
    uint4 q3 = Xr[(size_t)p3.x * NSQ + s];
    fma8(q0, __builtin_bit_cast(float, p0.y), acc);
    fma8(q1, __builtin_bit_cast(float, p1.y), acc);
    fma8(q2, __builtin_bit_cast(float, p2.y), acc);
    fma8(q3, __builtin_bit_cast(float, p3.y), acc);
  }
  for (; e < end; ++e) {
    uint2 p = pr[e];
    uint4 q = Xr[(size_t)p.x * NSQ + s];
    fma8(q, __builtin_bit_cast(float, p.y), acc);
  }
  uint4 o;
  o.x = pk2(acc[0], acc[1]);
  o.y = pk2(acc[2], acc[3]);
  o.z = pk2(acc[4], acc[5]);
  o.w = pk2(acc[6], acc[7]);
  reinterpret_cast<uint4*>(out)[(size_t)v * NSQ + s] = o;
}

// ---------------- bf16 MFMA GEMM (m97 structure): C[M,Nlog] = A[M,K] @ BT[*,K]^T ----------------
// 128x128 tile, BK=64, 4 waves 2x2, global_load_lds DMA staging, 2 barriers/K-step.
// LDS granule layout (k8, row): granule g = k8*128 + row, 16B each. Staging granule
// id = tid + 256j -> wave-uniform base + lane*16 (HW requirement). A rows clamped to
// M-1 (garbage rows land in discarded C rows); BT must have >= ntiles*128 valid rows.
// Grid: 1D, col-tile fastest + bijective XCD chunk swizzle (A-tile L2 reuse).
__global__ __launch_bounds__(256) void k_gemm(const unsigned short* __restrict__ A,
    const unsigned short* __restrict__ BT, unsigned short* __restrict__ C,
    int M, int Nlog, int K, int ntiles, int nwg) {
  constexpr int BK = 64;
  __shared__ unsigned short lA[(BK / 8) * 128 * 8];  // 16 KB
  __shared__ unsigned short lB[(BK / 8) * 128 * 8];

  int p = blockIdx.x;
  int xcd = p & 7, idx = p >> 3;
  int q8 = nwg >> 3, r8 = nwg & 7;
  int logical = (xcd < r8 ? xcd * (q8 + 1) : r8 * (q8 + 1) + (xcd - r8) * q8) + idx;
  const int nt = logical % ntiles;
  const int mt = logical / ntiles;
  const int m0 = mt * 128, n0 = nt * 128;

  const int tid = threadIdx.x, lane = tid & 63, wid = tid >> 6;
  const int wr = wid >> 1, wc = wid & 1;
  const int fr = lane & 15, fq = lane >> 4;

  // per-thread staging rows (granules tid+256j): row = g&127, k8 = g>>7
  int arow[4], brow[4], k8s[4];
#pragma unroll
  for (int j = 0; j < 4; ++j) {
    int g = tid + 256 * j;
    int row = g & 127;
    k8s[j] = g >> 7;
    int ar = m0 + row;
    arow[j] = (ar < M) ? ar : (M - 1);  // clamp: stays in-bounds, result discarded
    brow[j] = n0 + row;                 // BT padded: always valid
  }

  f32x4 acc[4][4] = {};

  for (int k0 = 0; k0 < K; k0 += BK) {
    __syncthreads();  // all waves done reading previous tile
#pragma unroll
    for (int j = 0; j < 4; ++j) {
      int g = tid + 256 * j;
      gload16(A  + (size_t)arow[j] * K + k0 + k8s[j] * 8, &lA[g * 8]);
      gload16(BT + (size_t)brow[j] * K + k0 + k8s[j] * 8, &lB[g * 8]);
    }
    __syncthreads();  // compiler drains vmcnt(0) before barrier -> LDS ready
#pragma unroll
    for (int step = 0; step < 2; ++step) {
      bf16x8 af[4], bf[4];
#pragma unroll
      for (int m = 0; m < 4; ++m)
        af[m] = *reinterpret_cast<const bf16x8*>(
            &lA[(((step * 4 + fq) << 7) + wr * 64 + m * 16 + fr) * 8]);
#pragma unroll
      for (int nn = 0; nn < 4; ++nn)
        bf[nn] = *reinterpret_cast<const bf16x8*>(
            &lB[(((step * 4 + fq) << 7) + wc * 64 + nn * 16 + fr) * 8]);
#pragma unroll
      for (int m = 0; m < 4; ++m)
#pragma unroll
        for (int nn = 0; nn < 4; ++nn)
          acc[m][nn] = __builtin_amdgcn_mfma_f32_16x16x32_bf16(af[m], bf[nn], acc[m][nn], 0, 0, 0);
    }
  }

#pragma unroll
  for (int m = 0; m < 4; ++m) {
#pragma unroll
    for (int r = 0; r < 4; ++r) {
      int row = m0 + wr * 64 + m * 16 + fq * 4 + r;
      if (row >= M) continue;
#pragma unroll
      for (int nn = 0; nn < 4; ++nn) {
        int col = n0 + wc * 64 + nn * 16 + fr;
        if (col < Nlog)
          C[(size_t)row * Nlog + col] = f2bf(acc[m][nn][r]);
      }
    }
  }
}

// ---------------- BatchNorm ----------------
__global__ void k_bn_stats_bf16(const unsigned short* __restrict__ H, float* __restrict__ s1,
                                float* __restrict__ s2, int n, int C, int stride, int rpb) {
  int r0 = blockIdx.x * rpb;
  int r1 = r0 + rpb;
  if (r1 > n) r1 = n;
  for (int c = threadIdx.x; c < C; c += blockDim.x) {
    float a = 0.f, b = 0.f;
    for (int r = r0; r < r1; ++r) {
      float v = bf2f(H[(size_t)r * stride + c]);
      a += v;
      b = fmaf(v, v, b);
    }
    atomAddF(&s1[c], a);
    atomAddF(&s2[c], b);
  }
}

__global__ void k_bn_finalize(const float* __restrict__ s1, const float* __restrict__ s2,
                              const float* __restrict__ g, const float* __restrict__ beta,
                              float* __restrict__ scale, float* __restrict__ shift,
                              int C, float invN) {
  int c = blockIdx.x * blockDim.x + threadIdx.x;
  if (c >= C) return;
  float mean = s1[c] * invN;
  float var = fmaxf(s2[c] * invN - mean * mean, 0.f);
  float sc = g[c] * rsqrtf(var + kEps);
  scale[c] = sc;
  shift[c] = beta[c] - mean * sc;
}

// in-place BN+ReLU on bf16 buffer, 8 elems/thread. C power of 2.
template<int C>
__global__ void k_bn_apply_relu_bf16(unsigned short* __restrict__ H,
                                     const float* __restrict__ scale,
                                     const float* __restrict__ shift, int total8) {
  int i = blockIdx.x * blockDim.x + threadIdx.x;
  if (i >= total8) return;
  uint4 q = reinterpret_cast<uint4*>(H)[i];
  int c = (i * 8) & (C - 1);
  unsigned w[4] = {q.x, q.y, q.z, q.w};
  unsigned o[4];
#pragma unroll
  for (int j = 0; j < 4; ++j) {
    float lo = blo(w[j]);
    float hi = bhi(w[j]);
    int cl = c + j * 2;
    lo = fmaxf(fmaf(lo, scale[cl],     shift[cl]),     0.f);
    hi = fmaxf(fmaf(hi, scale[cl + 1], shift[cl + 1]), 0.f);
    o[j] = pk2(lo, hi);
  }
  reinterpret_cast<uint4*>(H)[i] = make_uint4(o[0], o[1], o[2], o[3]);
}

// ---------------- head: BN2-apply + relu + @Wl + bl + relu + log_softmax ----------------
__global__ __launch_bounds__(256) void k_head(const unsigned short* __restrict__ H,
    const float* __restrict__ scale, const float* __restrict__ shift,
    const float* __restrict__ Wl, const float* __restrict__ bl,
    float* __restrict__ out, int n) {
  __shared__ float sW[kH2 * kOut];
  __shared__ float sScale[kH2], sShift[kH2];
  for (int i = threadIdx.x; i < kH2 * kOut; i += blockDim.x) sW[i] = Wl[i];
  for (int i = threadIdx.x; i < kH2; i += blockDim.x) {
    sScale[i] = scale[i];
    sShift[i] = shift[i];
  }
  __syncthreads();
  float blv[kOut];
#pragma unroll
  for (int j = 0; j < kOut; ++j) blv[j] = bl[j];
  const int lane = threadIdx.x & 63;
  const int wid = (blockIdx.x * blockDim.x + threadIdx.x) >> 6;
  const int nw  = (gridDim.x * blockDim.x) >> 6;
  for (int node = wid; node < n; node += nw) {
    const unsigned short* hrow = H + (size_t)node * kH2p;
    float acc[kOut] = {};
    for (int k = lane; k < kH2; k += 64) {
      float v = fmaxf(fmaf(bf2f(hrow[k]), sScale[k], sShift[k]), 0.f);
      const float* wr = sW + k * kOut;
#pragma unroll
      for (int j = 0; j < kOut; ++j) acc[j] = fmaf(v, wr[j], acc[j]);
    }
#pragma unroll
    for (int j = 0; j < kOut; ++j) {
      float v = acc[j];
      for (int off = 32; off > 0; off >>= 1) v += __shfl_down(v, off);
      acc[j] = v;
    }
    if (lane == 0) {
      float vv[kOut], m = -1e30f;
#pragma unroll
      for (int j = 0; j < kOut; ++j) {
        vv[j] = fmaxf(acc[j] + blv[j], 0.f);
        m = fmaxf(m, vv[j]);
      }
      float s = 0.f;
#pragma unroll
      for (int j = 0; j < kOut; ++j) s += expf(vv[j] - m);
      float lse = m + logf(s);
      float* o = out + (size_t)node * kOut;
#pragma unroll
      for (int j = 0; j < kOut; ++j) o[j] = vv[j] - lse;
    }
  }
}

}  // namespace

extern "C" void kernel_launch(void* const* d_in, const int* in_sizes, int n_in,
                              void* d_out, int out_size, void* d_ws, size_t ws_size,
                              hipStream_t stream) {
  const float* x   = (const float*)d_in[0];
  const int*   ei  = (const int*)d_in[1];
  const float* ew  = (const float*)d_in[2];
  const float* W1  = (const float*)d_in[3];
  // d_in[4] = b1: constant per column -> cancelled by BN1 mean subtraction
  const float* g1  = (const float*)d_in[5];
  const float* be1 = (const float*)d_in[6];
  const float* W2  = (const float*)d_in[7];
  // d_in[8] = b2: cancelled by BN2
  const float* g2  = (const float*)d_in[9];
  const float* be2 = (const float*)d_in[10];
  const float* Wl  = (const float*)d_in[11];
  const float* bl  = (const float*)d_in[12];
  float* out = (float*)d_out;
  float* ws  = (float*)d_ws;

  const int n = in_sizes[0] / kIn;  // 50000
  const int e = in_sizes[1] / 2;    // 800000

  // workspace (float units), ~145 MB total:
  float* dis = ws;                                         // 50048
  int*   cnt = (int*)(ws + 50048);                         // 50048
  uint2* pr  = (uint2*)(ws + 100096);                      // 800000 pairs
  float* st  = ws + 1700096;                               // 4096
  float* s1a = st,        *s2a = st + 512,  *sc1 = st + 1024, *sh1 = st + 1536;
  float* s1b = st + 2048, *s2b = st + 2560, *sc2 = st + 3072, *sh2 = st + 3584;
  unsigned short* xbf = (unsigned short*)(ws + 1704192);   // [n][128] = 3.2M fl
  unsigned short* W1T = (unsigned short*)(ws + 4904192);   // 512x128 = 32768 fl
  unsigned short* W2T = (unsigned short*)(ws + 4936960);   // 384x512 = 98304 fl
  unsigned short* agg1 = (unsigned short*)(ws + 5035264);  // [n][128] = 3.2M fl
  unsigned short* h1   = (unsigned short*)(ws + 8235264);  // [n][512] = 12.8M fl
  unsigned short* t2   = (unsigned short*)(ws + 21035264); // [n][304] = 7.6M fl
  unsigned short* agg2 = (unsigned short*)(ws + 28635264); // [n][304] = 7.6M fl

  constexpr int TPB = 256;

  // ---- fused prep + CSC build ----
  k_prep<<<(n * 16 + TPB - 1) / TPB, TPB, 0, stream>>>(dis, cnt, x, xbf, st, W1, W1T, W2, W2T, n);
  k_deg_cnt<<<(e + TPB - 1) / TPB, TPB, 0, stream>>>(dis, cnt, ei, ew, e);
  k_dis<<<(n + TPB - 1) / TPB, TPB, 0, stream>>>(dis, n);
  k_scan<<<1, 1024, 0, stream>>>(cnt, n);
  k_scatter<<<(e + TPB - 1) / TPB, TPB, 0, stream>>>(cnt, ei, ew, dis, pr, e);

  const int mtiles = (n + 127) / 128;  // 391

  // ---- layer 1: agg1 = A(xbf); h1 = bf16(agg1@W1); BN1 stats; in-place BN+ReLU ----
  {
    int tot = n * (kIn / 8);
    k_gather<kIn / 8><<<(tot + TPB - 1) / TPB, TPB, 0, stream>>>(xbf, cnt, pr, dis, agg1, n);
  }
  {
    int ntiles = kH1 / 128;            // 4
    int nwg = mtiles * ntiles;
    k_gemm<<<nwg, 256, 0, stream>>>(agg1, W1T, h1, n, kH1, kIn, ntiles, nwg);
  }
  k_bn_stats_bf16<<<512, 256, 0, stream>>>(h1, s1a, s2a, n, kH1, kH1, (n + 511) / 512);
  k_bn_finalize<<<(kH1 + 255) / 256, 256, 0, stream>>>(s1a, s2a, g1, be1, sc1, sh1, kH1, 1.0f / n);
  k_bn_apply_relu_bf16<kH1><<<((n * (kH1 / 8)) + TPB - 1) / TPB, TPB, 0, stream>>>(
      h1, sc1, sh1, n * (kH1 / 8));

  // ---- layer 2: t2 = bf16(h1@W2); agg2 = A(t2); BN2 stats ----
  {
    int ntiles = kW2R / 128;           // 3
    int nwg = mtiles * ntiles;
    k_gemm<<<nwg, 256, 0, stream>>>(h1, W2T, t2, n, kH2p, kH1, ntiles, nwg);
  }
  {
    int tot = n * (kH2p / 8);
    k_gather<kH2p / 8><<<(tot + TPB - 1) / TPB, TPB, 0, stream>>>(t2, cnt, pr, dis, agg2, n);
  }
  k_bn_stats_bf16<<<512, 256, 0, stream>>>(agg2, s1b, s2b, n, kH2, kH2p, (n + 511) / 512);
  k_bn_finalize<<<(kH2 + 255) / 256, 256, 0, stream>>>(s1b, s2b, g2, be2, sc2, sh2, kH2, 1.0f / n);

  // ---- head ----
  k_head<<<1024, 256, 0, stream>>>(agg2, sc2, sh2, Wl, bl, out, n);
}